// Round 2
// baseline (309.896 us; speedup 1.0000x reference)
//
#include <hip/hip_runtime.h>

#define NDATES 64
#define MASSETS 64
#define NSIMS 32768
#define SB 64   // sims per block

typedef __attribute__((ext_vector_type(8))) short bf16x8;
typedef __attribute__((ext_vector_type(4))) float f32x4;

__device__ __forceinline__ unsigned short f2bf(float f) {
    union { float f; unsigned u; } c; c.f = f;
    unsigned x = c.u;
    x += 0x7FFFu + ((x >> 16) & 1u);   // round-to-nearest-even
    return (unsigned short)(x >> 16);
}

// one-time cov f32 -> bf16 into workspace (removes per-date cvt from hot loop)
__global__ __launch_bounds__(256) void cov_prep_kernel(
    const float* __restrict__ cov, unsigned short* __restrict__ cw)
{
    const int i = (blockIdx.x * 256 + threadIdx.x) * 4;
    const float4 v = *reinterpret_cast<const float4*>(cov + i);
    ushort4 o;
    o.x = f2bf(v.x); o.y = f2bf(v.y); o.z = f2bf(v.z); o.w = f2bf(v.w);
    *reinterpret_cast<ushort4*>(cw + i) = o;
}

__global__ __launch_bounds__(256) void evo_lognormal_kernel(
    const unsigned short* __restrict__ cw,  // cov bf16 [64][64][64]
    const float* __restrict__ var,          // [64][64]
    const float* __restrict__ z,            // [64][64][32768]
    float* __restrict__ out)                // [64][64][32768]
{
    // z tile for one date, sim-major [s][k] bf16, XOR-swizzled: k ^ ((s&7)<<3)
    __shared__ __align__(16) unsigned short zs[SB * 64];

    const int t    = threadIdx.x;     // 0..255
    const int wv   = t >> 6;          // wave 0..3 -> 16-sim tile
    const int lane = t & 63;
    const int Q    = lane >> 2;       // 0..15
    const int q    = lane & 3;        // 0..3
    const int l15  = lane & 15;
    const int lg   = lane >> 4;       // 0..3
    const int s0   = blockIdx.x * SB;

    // acc[ct]: D[sim = wv*16 + lg*4 + reg][asset = ct*16 + l15]
    f32x4 acc[4];
    #pragma unroll
    for (int i = 0; i < 4; ++i) acc[i] = f32x4{0.f, 0.f, 0.f, 0.f};
    float vs[4] = {0.f, 0.f, 0.f, 0.f};

    const int srow = wv * 16 + l15;          // this lane's A (z) sim row in LDS
    const int ard  = srow * 64 + ((lg << 3) ^ ((l15 & 7) << 3));

    // raw z prefetch registers (date d+1 loads issued during date d compute)
    float4 zr[4];
    const float* zb = z + s0;
    {
        #pragma unroll
        for (int it = 0; it < 4; ++it) {
            const int kb = it * 16 + wv * 4;
            zr[it] = *reinterpret_cast<const float4*>(zb + (size_t)(kb + q) * NSIMS + 4 * Q);
        }
    }

    for (int d = 0; d < NDATES; ++d) {
        if (d) __syncthreads();   // previous date's LDS reads done before overwrite

        // ---- transpose+cvt prefetched z regs -> LDS [s][k] bf16 (swizzled) ----
        #pragma unroll
        for (int it = 0; it < 4; ++it) {
            const int kb = it * 16 + wv * 4;
            float v0 = zr[it].x, v1 = zr[it].y, v2 = zr[it].z, v3 = zr[it].w;
            // 4x4 transpose within the quad (lanes 4Q..4Q+3) via shfl_xor
            float s01 = __shfl_xor(v1, 1), s10 = __shfl_xor(v0, 1);
            float s23 = __shfl_xor(v3, 1), s32 = __shfl_xor(v2, 1);
            float a0 = (q & 1) ? s01 : v0;
            float a1 = (q & 1) ? v1  : s10;
            float a2 = (q & 1) ? s23 : v2;
            float a3 = (q & 1) ? v3  : s32;
            float u02 = __shfl_xor(a2, 2), u20 = __shfl_xor(a0, 2);
            float u13 = __shfl_xor(a3, 2), u31 = __shfl_xor(a1, 2);
            float w0 = (q & 2) ? u02 : a0;
            float w1 = (q & 2) ? u13 : a1;
            float w2 = (q & 2) ? a2  : u20;
            float w3 = (q & 2) ? a3  : u31;
            // this thread now holds z[kb+0..3][s0 + 4Q + q]
            const int sh = 4 * Q + q;
            unsigned lo = (unsigned)f2bf(w0) | ((unsigned)f2bf(w1) << 16);
            unsigned hi = (unsigned)f2bf(w2) | ((unsigned)f2bf(w3) << 16);
            const int u = sh * 64 + (kb ^ ((sh & 7) << 3));
            *reinterpret_cast<uint2*>(&zs[u]) = make_uint2(lo, hi);
        }

        __syncthreads();   // tile staged

        // ---- issue next date's z loads now; they overlap MFMA + stores ----
        if (d + 1 < NDATES) {
            const float* zd = zb + ((size_t)(d + 1) << 21);
            #pragma unroll
            for (int it = 0; it < 4; ++it) {
                const int kb = it * 16 + wv * 4;
                zr[it] = *reinterpret_cast<const float4*>(zd + (size_t)(kb + q) * NSIMS + 4 * Q);
            }
        }

        // ---- A frags (z) from LDS: 2 x ds_read_b128 ----
        bf16x8 a0 = *reinterpret_cast<const bf16x8*>(&zs[ard]);
        bf16x8 a1 = *reinterpret_cast<const bf16x8*>(&zs[ard ^ 32]);

        // ---- MFMA: acc never resets -> cumsum over dates is free ----
        const unsigned short* cb = cw + (((d << 6) + l15) << 6) + (lg << 3);
        #pragma unroll
        for (int ct = 0; ct < 4; ++ct) {
            bf16x8 b0 = *reinterpret_cast<const bf16x8*>(cb + (ct << 10));
            bf16x8 b1 = *reinterpret_cast<const bf16x8*>(cb + (ct << 10) + 32);
            acc[ct] = __builtin_amdgcn_mfma_f32_16x16x32_bf16(a0, b0, acc[ct], 0, 0, 0);
            acc[ct] = __builtin_amdgcn_mfma_f32_16x16x32_bf16(a1, b1, acc[ct], 0, 0, 0);
        }

        // ---- running var/2 cumsum: vs[ct] for asset = ct*16 + l15 ----
        const float* vp = var + (d << 6) + l15;
        #pragma unroll
        for (int ct = 0; ct < 4; ++ct) vs[ct] += 0.5f * vp[ct << 4];

        // ---- store: 4 x float4 (4 consecutive sims per lane) ----
        float* ob = out + (((size_t)d << 21)) + s0 + wv * 16 + (lg << 2);
        #pragma unroll
        for (int ct = 0; ct < 4; ++ct) {
            float4 o;
            o.x = acc[ct][0] - vs[ct];
            o.y = acc[ct][1] - vs[ct];
            o.z = acc[ct][2] - vs[ct];
            o.w = acc[ct][3] - vs[ct];
            *reinterpret_cast<float4*>(ob + ((size_t)(ct * 16 + l15) << 15)) = o;
        }
    }
}

extern "C" void kernel_launch(void* const* d_in, const int* in_sizes, int n_in,
                              void* d_out, int out_size, void* d_ws, size_t ws_size,
                              hipStream_t stream) {
    const float* cov = (const float*)d_in[0];
    const float* var = (const float*)d_in[1];
    const float* z   = (const float*)d_in[2];
    float* out = (float*)d_out;
    unsigned short* cw = (unsigned short*)d_ws;   // 512 KB bf16 cov

    cov_prep_kernel<<<dim3(NDATES * MASSETS * MASSETS / 1024), dim3(256), 0, stream>>>(cov, cw);
    evo_lognormal_kernel<<<dim3(NSIMS / SB), dim3(256), 0, stream>>>(cw, var, z, out);
}

// Round 7
// 289.901 us; speedup vs baseline: 1.0690x; 1.0690x over previous
//
#include <hip/hip_runtime.h>

#define NDATES 64
#define MASSETS 64
#define NSIMS 32768
#define SB 64   // sims per block -> 512 blocks

typedef __attribute__((ext_vector_type(8))) short bf16x8;
typedef __attribute__((ext_vector_type(4))) float f32x4;

__device__ __forceinline__ unsigned short f2bf(float f) {
    union { float f; unsigned u; } c; c.f = f;
    unsigned x = c.u;
    x += 0x7FFFu + ((x >> 16) & 1u);   // round-to-nearest-even
    return (unsigned short)(x >> 16);
}

// prep: cov f32 -> bf16, linear layout (R2-validated)
__global__ __launch_bounds__(256) void cov_prep_kernel(
    const float* __restrict__ cov, unsigned short* __restrict__ cw)
{
    const int g = (blockIdx.x * 256 + threadIdx.x) * 4;
    const float4 v = *reinterpret_cast<const float4*>(cov + g);
    ushort4 o;
    o.x = f2bf(v.x); o.y = f2bf(v.y); o.z = f2bf(v.z); o.w = f2bf(v.w);
    *reinterpret_cast<ushort4*>(cw + g) = o;
}

__global__ __launch_bounds__(256) void evo_lognormal_kernel(
    const unsigned short* __restrict__ cw,  // cov bf16 [64][64][64], linear
    const float* __restrict__ var,          // [64][64]
    const float* __restrict__ z,            // [64][64][32768]
    float* __restrict__ out)                // [64][64][32768]
{
    // z tile, sim-major [s][k] bf16, XOR-swizzled: k ^ ((s&7)<<3)  (R1/R2-validated)
    __shared__ __align__(16) unsigned short zs[SB * 64];

    const int t    = threadIdx.x;     // 0..255
    const int wv   = t >> 6;          // wave 0..3
    const int lane = t & 63;
    const int Q    = lane >> 2;       // 0..15
    const int q    = lane & 3;        // 0..3
    const int l15  = lane & 15;
    const int lg   = lane >> 4;       // 0..3
    const int s0   = blockIdx.x * SB;

    // acc[ct]: D[sim = wv*16 + lg*4 + reg][asset = ct*16 + l15]  (R2-validated)
    f32x4 acc[4];
    #pragma unroll
    for (int i = 0; i < 4; ++i) acc[i] = f32x4{0.f, 0.f, 0.f, 0.f};
    float vs[4] = {0.f, 0.f, 0.f, 0.f};

    const int srow = wv * 16 + l15;          // this lane's A (z) sim row in LDS
    const int ard  = srow * 64 + ((lg << 3) ^ ((l15 & 7) << 3));
    const unsigned short* cb0 = cw + l15 * 64 + (lg << 3);

    // prologue: date-0 z into named regs (R2-validated addressing)
    const float* zbp = z + s0;
    float4 zr0 = *reinterpret_cast<const float4*>(zbp + (size_t)( 0 + wv * 4 + q) * NSIMS + 4 * Q);
    float4 zr1 = *reinterpret_cast<const float4*>(zbp + (size_t)(16 + wv * 4 + q) * NSIMS + 4 * Q);
    float4 zr2 = *reinterpret_cast<const float4*>(zbp + (size_t)(32 + wv * 4 + q) * NSIMS + 4 * Q);
    float4 zr3 = *reinterpret_cast<const float4*>(zbp + (size_t)(48 + wv * 4 + q) * NSIMS + 4 * Q);

    // R2-validated transpose+cvt+swizzled-store of one 16k x 64s slab
    auto stage = [&](int it, const float4& v4) {
        const int kb = it * 16 + wv * 4;
        float v0 = v4.x, v1 = v4.y, v2 = v4.z, v3 = v4.w;
        float s01 = __shfl_xor(v1, 1), s10 = __shfl_xor(v0, 1);
        float s23 = __shfl_xor(v3, 1), s32 = __shfl_xor(v2, 1);
        float a0 = (q & 1) ? s01 : v0;
        float a1 = (q & 1) ? v1  : s10;
        float a2 = (q & 1) ? s23 : v2;
        float a3 = (q & 1) ? v3  : s32;
        float u02 = __shfl_xor(a2, 2), u20 = __shfl_xor(a0, 2);
        float u13 = __shfl_xor(a3, 2), u31 = __shfl_xor(a1, 2);
        float w0 = (q & 2) ? u02 : a0;
        float w1 = (q & 2) ? u13 : a1;
        float w2 = (q & 2) ? a2  : u20;
        float w3 = (q & 2) ? a3  : u31;
        const int sh = 4 * Q + q;
        unsigned lo = (unsigned)f2bf(w0) | ((unsigned)f2bf(w1) << 16);
        unsigned hi = (unsigned)f2bf(w2) | ((unsigned)f2bf(w3) << 16);
        const int u = sh * 64 + (kb ^ ((sh & 7) << 3));
        *reinterpret_cast<uint2*>(&zs[u]) = make_uint2(lo, hi);
    };

    for (int d = 0; d < NDATES; ++d) {
        // ---- B frags FIRST (global bf16, L2-resident): latency hides under staging ----
        const unsigned short* cr = cb0 + (d << 12);
        bf16x8 b[4][2];
        #pragma unroll
        for (int ct = 0; ct < 4; ++ct)
            #pragma unroll
            for (int kk = 0; kk < 2; ++kk)
                b[ct][kk] = *reinterpret_cast<const bf16x8*>(cr + (ct << 10) + kk * 32);

        if (d) __syncthreads();   // prev date's LDS reads done before overwrite

        // ---- stage date d: transpose + cvt + swizzled LDS write (R2 verbatim) ----
        stage(0, zr0); stage(1, zr1); stage(2, zr2); stage(3, zr3);

        // ---- issue next date's z loads before the barrier; consumed next iter ----
        if (d + 1 < NDATES) {
            const float* zn = zbp + ((size_t)(d + 1) << 21);
            zr0 = *reinterpret_cast<const float4*>(zn + (size_t)( 0 + wv * 4 + q) * NSIMS + 4 * Q);
            zr1 = *reinterpret_cast<const float4*>(zn + (size_t)(16 + wv * 4 + q) * NSIMS + 4 * Q);
            zr2 = *reinterpret_cast<const float4*>(zn + (size_t)(32 + wv * 4 + q) * NSIMS + 4 * Q);
            zr3 = *reinterpret_cast<const float4*>(zn + (size_t)(48 + wv * 4 + q) * NSIMS + 4 * Q);
        }

        __syncthreads();   // tile staged

        // ---- A frags: 2 x ds_read_b128 (R2 verbatim) ----
        bf16x8 a0 = *reinterpret_cast<const bf16x8*>(&zs[ard]);
        bf16x8 a1 = *reinterpret_cast<const bf16x8*>(&zs[ard ^ 32]);

        // ---- MFMA: acc never resets -> date-cumsum is free (R2 verbatim) ----
        #pragma unroll
        for (int ct = 0; ct < 4; ++ct) {
            acc[ct] = __builtin_amdgcn_mfma_f32_16x16x32_bf16(a0, b[ct][0], acc[ct], 0, 0, 0);
            acc[ct] = __builtin_amdgcn_mfma_f32_16x16x32_bf16(a1, b[ct][1], acc[ct], 0, 0, 0);
        }

        // ---- var running sum (R2 verbatim) ----
        const float* vp = var + (d << 6) + l15;
        #pragma unroll
        for (int ct = 0; ct < 4; ++ct) vs[ct] += 0.5f * vp[ct << 4];

        // ---- store: 4 x float4, 4 consecutive sims per lane (R2 verbatim) ----
        float* ob = out + ((size_t)d << 21) + s0 + wv * 16 + (lg << 2);
        #pragma unroll
        for (int ct = 0; ct < 4; ++ct) {
            float4 o;
            o.x = acc[ct][0] - vs[ct];
            o.y = acc[ct][1] - vs[ct];
            o.z = acc[ct][2] - vs[ct];
            o.w = acc[ct][3] - vs[ct];
            *reinterpret_cast<float4*>(ob + ((size_t)(ct * 16 + l15) << 15)) = o;
        }
    }
}

extern "C" void kernel_launch(void* const* d_in, const int* in_sizes, int n_in,
                              void* d_out, int out_size, void* d_ws, size_t ws_size,
                              hipStream_t stream) {
    const float* cov = (const float*)d_in[0];
    const float* var = (const float*)d_in[1];
    const float* z   = (const float*)d_in[2];
    float* out = (float*)d_out;
    unsigned short* cw = (unsigned short*)d_ws;   // 512 KB bf16 cov (linear)

    cov_prep_kernel<<<dim3(NDATES * MASSETS * MASSETS / 1024), dim3(256), 0, stream>>>(cov, cw);
    evo_lognormal_kernel<<<dim3(NSIMS / SB), dim3(256), 0, stream>>>(cw, var, z, out);
}